// Round 6
// baseline (239.750 us; speedup 1.0000x reference)
//
#include <hip/hip_runtime.h>

#define BSEG  16384
#define NPART 256
#define TILE  8                       // 512-elem tiles per wave
#define WAVE_SPAN (512LL * TILE)      // 4096 elements per wave
// ws layout: seg_in[BSEG] f32, seg_tg[BSEG] f32, elem_part[NPART] f64
#define WS_BYTES (2 * BSEG * 4 + NPART * 8)

__global__ __launch_bounds__(256) void main_pass(
        const float* __restrict__ in, const float* __restrict__ tg,
        const int* __restrict__ batch,
        float* __restrict__ seg_in, float* __restrict__ seg_tg,
        double* __restrict__ elem_part, int n)
{
    const int lane = threadIdx.x & 63;
    const int gw   = (blockIdx.x * blockDim.x + threadIdx.x) >> 6;   // global wave id
    const long long waveBase = (long long)gw * WAVE_SPAN;

    float elem = 0.0f;
    int   carryId = -1;               // last run carried across tiles (wave-uniform)
    float carrySi = 0.0f, carrySt = 0.0f;

    // ---- preload tile 0 ----
    float4 a0, a1, t0, t1; int4 b0, b1;
    {
        long long i0 = waveBase + (long long)lane * 8;
        if (i0 < n) {
            a0 = ((const float4*)(in + i0))[0];  a1 = ((const float4*)(in + i0))[1];
            t0 = ((const float4*)(tg + i0))[0];  t1 = ((const float4*)(tg + i0))[1];
            b0 = ((const int4*)(batch + i0))[0]; b1 = ((const int4*)(batch + i0))[1];
        }
    }

    #pragma unroll
    for (int t = 0; t < TILE; ++t) {
        const long long i0 = waveBase + (long long)t * 512 + (long long)lane * 8;
        const bool live = (i0 < n);

        // ---- prefetch tile t+1 (overlaps this tile's scan chain) ----
        float4 na0, na1, nt0, nt1; int4 nb0, nb1;
        if (t + 1 < TILE) {
            long long ni0 = waveBase + (long long)(t + 1) * 512 + (long long)lane * 8;
            if (ni0 < n) {
                na0 = ((const float4*)(in + ni0))[0];  na1 = ((const float4*)(in + ni0))[1];
                nt0 = ((const float4*)(tg + ni0))[0];  nt1 = ((const float4*)(tg + ni0))[1];
                nb0 = ((const int4*)(batch + ni0))[0]; nb1 = ((const int4*)(batch + ni0))[1];
            }
        }

        // ---- per-thread 8-elem accumulate (interior boundaries flush direct) ----
        int   cur = -2;               // dead-lane sentinel (never equals a real id / -1)
        float si = 0.0f, st = 0.0f;
        if (live) {
            float vi[8] = {a0.x, a0.y, a0.z, a0.w, a1.x, a1.y, a1.z, a1.w};
            float vt[8] = {t0.x, t0.y, t0.z, t0.w, t1.x, t1.y, t1.z, t1.w};
            int   vb[8] = {b0.x, b0.y, b0.z, b0.w, b1.x, b1.y, b1.z, b1.w};
            cur = vb[0];
            #pragma unroll
            for (int j = 0; j < 8; ++j) {
                float x = vi[j], y = vt[j];
                float d = fabsf(x) - fabsf(y);
                elem = fmaf(d, d, elem);
                int b = vb[j];
                if (b != cur) {                       // rare (~0.65% of threads)
                    atomicAdd(seg_in + cur, si);
                    atomicAdd(seg_tg + cur, st);
                    cur = b; si = 0.0f; st = 0.0f;
                }
                si += x; st += y;
            }
        }

        // ---- wave segmented scan; sorted ids => segment test is id equality ----
        #pragma unroll
        for (int d = 1; d < 64; d <<= 1) {
            float o1 = __shfl_up(si, d);
            float o2 = __shfl_up(st, d);
            int  oid = __shfl_up(cur, d);
            if (lane >= d && oid == cur) { si += o1; st += o2; }
        }
        const int   firstId = __shfl(cur, 0);
        const int   lastId  = __shfl(cur, 63);
        const float lastSi  = __shfl(si, 63);
        const float lastSt  = __shfl(st, 63);
        const int   nextId  = __shfl_down(cur, 1);
        const bool  isTail  = (lane == 63) || (nextId != cur);

        // old carry that can't merge into this tile's first run: flush it
        if (lane == 0 && carryId >= 0 && carryId != firstId) {
            atomicAdd(seg_in + carryId, carrySi);
            atomicAdd(seg_tg + carryId, carrySt);
        }
        // flush every completed run (tails not belonging to the last run)
        if (isTail && cur >= 0 && cur != lastId) {
            float fi = si, ft = st;
            if (cur == firstId && carryId == firstId) { fi += carrySi; ft += carrySt; }
            atomicAdd(seg_in + cur, fi);
            atomicAdd(seg_tg + cur, ft);
        }
        // new carry = this tile's last run (or clear if tile tail is dead)
        if (lastId >= 0) {
            if (carryId == lastId && firstId == lastId) { carrySi += lastSi; carrySt += lastSt; }
            else                                        { carrySi  = lastSi; carrySt  = lastSt; }
            carryId = lastId;
        } else {                       // dead tail: everything real was flushed above
            carryId = -1; carrySi = 0.0f; carrySt = 0.0f;
        }

        // rotate prefetched regs in
        if (t + 1 < TILE) { a0 = na0; a1 = na1; t0 = nt0; t1 = nt1; b0 = nb0; b1 = nb1; }
    }

    // final carry flush (carry regs are wave-uniform via the lane-63 broadcast)
    if (lane == 0 && carryId >= 0) {
        atomicAdd(seg_in + carryId, carrySi);
        atomicAdd(seg_tg + carryId, carrySt);
    }

    // ---- block-reduce elementwise loss -> 256 partial slots ----
    #pragma unroll
    for (int off = 32; off; off >>= 1) elem += __shfl_xor(elem, off);
    __shared__ float wsum[4];
    int wid = threadIdx.x >> 6;
    if (lane == 0) wsum[wid] = elem;
    __syncthreads();
    if (threadIdx.x == 0) {
        float s = wsum[0] + wsum[1] + wsum[2] + wsum[3];
        atomicAdd(elem_part + (blockIdx.x & (NPART - 1)), (double)s);
    }
}

__global__ __launch_bounds__(1024) void finalize_kernel(
        const float* __restrict__ seg_in, const float* __restrict__ seg_tg,
        const double* __restrict__ elem_part, float* __restrict__ out)
{
    const float4* s4 = (const float4*)seg_in;
    const float4* g4 = (const float4*)seg_tg;
    double acc = 0.0;
    for (int i = threadIdx.x; i < BSEG / 4; i += 1024) {
        float4 a = s4[i], b = g4[i];
        float d0 = a.x * a.x - b.x * b.x;
        float d1 = a.y * a.y - b.y * b.y;
        float d2 = a.z * a.z - b.z * b.z;
        float d3 = a.w * a.w - b.w * b.w;
        acc += (double)d0 * d0 + (double)d1 * d1 + (double)d2 * d2 + (double)d3 * d3;
    }
    if (threadIdx.x < NPART) acc += elem_part[threadIdx.x];
    #pragma unroll
    for (int off = 32; off; off >>= 1) acc += __shfl_xor(acc, off);
    __shared__ double wsum[16];
    int lane = threadIdx.x & 63, wid = threadIdx.x >> 6;
    if (lane == 0) wsum[wid] = acc;
    __syncthreads();
    if (threadIdx.x == 0) {
        double t = 0.0;
        #pragma unroll
        for (int w = 0; w < 16; ++w) t += wsum[w];
        out[0] = (float)t;
    }
}

extern "C" void kernel_launch(void* const* d_in, const int* in_sizes, int n_in,
                              void* d_out, int out_size, void* d_ws, size_t ws_size,
                              hipStream_t stream) {
    const float* in    = (const float*)d_in[0];
    const float* tg    = (const float*)d_in[1];
    const int*   batch = (const int*)d_in[2];
    const int n = in_sizes[0];

    float*  seg_in    = (float*)d_ws;
    float*  seg_tg    = seg_in + BSEG;
    double* elem_part = (double*)(seg_in + 2 * BSEG);
    float*  out       = (float*)d_out;

    hipMemsetAsync(d_ws, 0, WS_BYTES, stream);

    const int nWaves = (int)((n + WAVE_SPAN - 1) / WAVE_SPAN);
    const int blocks = (nWaves + 3) / 4;            // 256 threads = 4 waves/block
    main_pass<<<blocks, 256, 0, stream>>>(in, tg, batch, seg_in, seg_tg, elem_part, n);

    finalize_kernel<<<1, 1024, 0, stream>>>(seg_in, seg_tg, elem_part, out);
}